// Round 13
// baseline (427.564 us; speedup 1.0000x reference)
//
#include <hip/hip_runtime.h>
#include <math.h>

namespace {

constexpr int BT  = 8 * 4096;   // 32768 tokens
constexpr int DIM = 1024;       // model dim
constexpr int NE  = 64;         // experts
constexpr int NS  = 8;          // slots per expert
constexpr int NP  = NE * NS;    // 512 total slots
constexpr int HID = 256;
constexpr int LDT = BT + 32;    // 32800: padded row stride for [*][BT] arrays
                                // (breaks 64KB pow-2 stride -> L2 channel aliasing)

typedef float f32x4 __attribute__((ext_vector_type(4)));
typedef __bf16 bf16x8 __attribute__((ext_vector_type(8)));
typedef short s16x8 __attribute__((ext_vector_type(8)));

__device__ __forceinline__ ushort f2bf(float x) {
  union { float f; unsigned u; } a; a.f = x;
  unsigned r = a.u + 0x7FFFu + ((a.u >> 16) & 1u);  // RNE
  return (ushort)(r >> 16);
}
__device__ __forceinline__ float bf2f(ushort u) {
  union { unsigned u; float f; } a; a.u = (unsigned)u << 16;
  return a.f;
}

__device__ __forceinline__ void gload16(const void* g, void* l) {
  __builtin_amdgcn_global_load_lds(
      (const __attribute__((address_space(1))) void*)g,
      (__attribute__((address_space(3))) void*)l, 16, 0, 0);
}

// ---------------------------------------------------------------------------
// bf16 MFMA GEMM — structure UNCHANGED from round 11 (measured win); only
// addition: explicit lda/ldb element strides so A/B may be pad-strided.
// Tile 256(M)x128(N), BK=64, 8 waves, 3-buffer rotation, one s_barrier +
// counted vmcnt(6) per K-tile, LDS XOR swizzle both-sides, T1 XCD swizzle.
// ---------------------------------------------------------------------------
template <bool ATOMIC, bool OBF>
__global__ __launch_bounds__(512) void k_gemm(const ushort* __restrict__ A,
                                              const ushort* __restrict__ Bt,
                                              void* __restrict__ Cv,
                                              int N, int kchunk,
                                              int lda, int ldb) {
  __shared__ __align__(16) ushort As0[256 * 64];
  __shared__ __align__(16) ushort As1[256 * 64];
  __shared__ __align__(16) ushort As2[256 * 64];
  __shared__ __align__(16) ushort Bs0[128 * 64];
  __shared__ __align__(16) ushort Bs1[128 * 64];
  __shared__ __align__(16) ushort Bs2[128 * 64];

  const int tid = threadIdx.x;
  const int wid = tid >> 6;
  const int lane = tid & 63;

  // T1 XCD-chunked swizzle (bijective: nwg % 8 == 0)
  const int gx = gridDim.x, gy = gridDim.y;
  int wg = (blockIdx.z * gy + blockIdx.y) * gx + blockIdx.x;
  const int nwg = gx * gy * gridDim.z;
  wg = (wg & 7) * (nwg >> 3) + (wg >> 3);
  const int bx = wg % gx;
  const int rest = wg / gx;
  const int by = rest % gy;
  const int bz = rest / gy;

  const int n0 = bx * 128;
  const int m0 = by * 256;
  const int kb = bz * kchunk;

  const int w8 = wid * 8;
  const int lr = lane >> 3;
  const int ks = (((lane & 7) ^ lr) * 8);
  const ushort* Asrc = A + (size_t)(m0 + w8 + lr) * lda + ks;
  const ushort* Bsrc = Bt + (size_t)(n0 + w8 + lr) * ldb + ks;

  const int wm64 = (wid >> 1) * 64;
  const int wn64 = (wid & 1) * 64;
  const int fr = lane & 15;
  const int fq = lane >> 4;
  const int fq8 = fq * 8;
  const int frsw = (fr & 7) << 3;

  f32x4 acc[4][4];
#pragma unroll
  for (int i = 0; i < 4; ++i)
#pragma unroll
    for (int j = 0; j < 4; ++j) acc[i][j] = (f32x4){0.f, 0.f, 0.f, 0.f};

  const int nt = kchunk / 64;

#define STAGE6(An_, Bn_, kt_)                                                    \
  do {                                                                           \
    _Pragma("unroll") for (int q = 0; q < 4; ++q)                                \
      gload16(Asrc + (size_t)(q * 64) * lda + (kt_), (An_) + (q * 64 + w8) * 64);\
    _Pragma("unroll") for (int q = 0; q < 2; ++q)                                \
      gload16(Bsrc + (size_t)(q * 64) * ldb + (kt_), (Bn_) + (q * 64 + w8) * 64);\
  } while (0)

#define LD(B_, r_, h_)                                                          \
  __builtin_bit_cast(bf16x8, *(const s16x8*)((B_) + (size_t)(r_) * 64 +         \
                                             (((h_) * 32 + fq8) ^ frsw)))

#define GBLOCK(Ab_, Bb_, An_, Bn_, tt_)                                         \
  do {                                                                          \
    if ((tt_) + 1 < nt) asm volatile("s_waitcnt vmcnt(6)" ::: "memory");        \
    else                asm volatile("s_waitcnt vmcnt(0)" ::: "memory");        \
    __builtin_amdgcn_sched_barrier(0);                                          \
    __builtin_amdgcn_s_barrier();                                               \
    __builtin_amdgcn_sched_barrier(0);                                          \
    if ((tt_) + 2 < nt) STAGE6(An_, Bn_, kb + ((tt_) + 2) * 64);                \
    bf16x8 bfr_[4][2];                                                          \
    _Pragma("unroll") for (int n = 0; n < 4; ++n) {                             \
      bfr_[n][0] = LD(Bb_, wn64 + n * 16 + fr, 0);                              \
      bfr_[n][1] = LD(Bb_, wn64 + n * 16 + fr, 1);                              \
    }                                                                           \
    _Pragma("unroll") for (int m = 0; m < 4; ++m) {                             \
      bf16x8 a0_ = LD(Ab_, wm64 + m * 16 + fr, 0);                              \
      bf16x8 a1_ = LD(Ab_, wm64 + m * 16 + fr, 1);                              \
      __builtin_amdgcn_s_setprio(1);                                            \
      _Pragma("unroll") for (int n = 0; n < 4; ++n)                             \
        acc[m][n] = __builtin_amdgcn_mfma_f32_16x16x32_bf16(a0_, bfr_[n][0],    \
                                                            acc[m][n], 0, 0, 0);\
      _Pragma("unroll") for (int n = 0; n < 4; ++n)                             \
        acc[m][n] = __builtin_amdgcn_mfma_f32_16x16x32_bf16(a1_, bfr_[n][1],    \
                                                            acc[m][n], 0, 0, 0);\
      __builtin_amdgcn_s_setprio(0);                                            \
    }                                                                           \
  } while (0)

  STAGE6(As0, Bs0, kb);
  STAGE6(As1, Bs1, kb + 64);
  int t = 0;
  for (; t + 3 <= nt; t += 3) {
    GBLOCK(As0, Bs0, As2, Bs2, t);
    GBLOCK(As1, Bs1, As0, Bs0, t + 1);
    GBLOCK(As2, Bs2, As1, Bs1, t + 2);
  }
  if (t < nt) { GBLOCK(As0, Bs0, As2, Bs2, t); ++t; }
  if (t < nt) { GBLOCK(As1, Bs1, As0, Bs0, t); ++t; }
#undef GBLOCK
#undef LD
#undef STAGE6

  // C/D layout: col = lane&15, row = (lane>>4)*4 + reg   [m89-verified]
  if (OBF) {
    ushort* Cb = (ushort*)Cv + (size_t)(m0 + wm64 + fq * 4) * N + n0 + wn64 + fr;
#pragma unroll
    for (int m = 0; m < 4; ++m)
#pragma unroll
      for (int n = 0; n < 4; ++n)
#pragma unroll
        for (int r = 0; r < 4; ++r)
          Cb[(size_t)(m * 16 + r) * N + n * 16] = f2bf(acc[m][n][r]);
  } else {
    float* Cb = (float*)Cv + (size_t)(m0 + wm64 + fq * 4) * N + n0 + wn64 + fr;
#pragma unroll
    for (int m = 0; m < 4; ++m)
#pragma unroll
      for (int n = 0; n < 4; ++n)
#pragma unroll
        for (int r = 0; r < 4; ++r) {
          float* p = Cb + (size_t)(m * 16 + r) * N + n * 16;
          if (ATOMIC) atomicAdd(p, acc[m][n][r]);
          else *p = acc[m][n][r];
        }
  }
}

// ---------------------------------------------------------------------------
// fp32 [R][C] -> bf16 rowmajor and/or bf16 transposed (row stride ldt).
// ---------------------------------------------------------------------------
template <bool ROWM, bool TRANSP>
__global__ __launch_bounds__(256) void k_cvt(const float* __restrict__ X,
                                             ushort* __restrict__ Yrm,
                                             ushort* __restrict__ Yt,
                                             int Cc, int ldt) {
  __shared__ __align__(16) ushort tT[64][64];
  const int tid = threadIdx.x;
  const int r0 = blockIdx.x * 64, c0 = blockIdx.y * 64;
#pragma unroll
  for (int i = 0; i < 4; ++i) {
    const int idx = i * 256 + tid;
    const int r = idx >> 4, c4 = (idx & 15) * 4;
    float4 v = *(const float4*)(X + (size_t)(r0 + r) * Cc + c0 + c4);
    ushort u[4] = {f2bf(v.x), f2bf(v.y), f2bf(v.z), f2bf(v.w)};
    if (ROWM) {
      ushort4 o = make_ushort4(u[0], u[1], u[2], u[3]);
      *(ushort4*)(Yrm + (size_t)(r0 + r) * Cc + c0 + c4) = o;
    }
    if (TRANSP) {
#pragma unroll
      for (int j = 0; j < 4; ++j)
        tT[c4 + j][r ^ (((c4 + j) & 7) << 3)] = u[j];
    }
  }
  if (TRANSP) {
    __syncthreads();
#pragma unroll
    for (int i = 0; i < 2; ++i) {
      const int idx = i * 256 + tid;
      const int c = idx >> 3, r8 = (idx & 7) * 8;
      s16x8 o = *(const s16x8*)&tT[c][r8 ^ ((c & 7) << 3)];
      *(s16x8*)(Yt + (size_t)(c0 + c) * ldt + r0 + r8) = o;
    }
  }
}

// ---------------------------------------------------------------------------
// Column softmax stats over bf16 mat. Block: 256 rows x all 512 cols.
// ---------------------------------------------------------------------------
__global__ __launch_bounds__(256) void k_colpart(const ushort* __restrict__ mat,
                                                 float* __restrict__ pm,
                                                 float* __restrict__ pz) {
  const int c8 = (threadIdx.x & 63) * 8;
  const int rq = threadIdx.x >> 6;
  const int r0 = blockIdx.x * 256;
  float m[8], z[8];
#pragma unroll
  for (int j = 0; j < 8; ++j) { m[j] = -INFINITY; z[j] = 0.f; }
  for (int r = r0 + rq; r < r0 + 256; r += 4) {
    s16x8 v = *(const s16x8*)(mat + (size_t)r * NP + c8);
#pragma unroll
    for (int j = 0; j < 8; ++j) {
      float f = bf2f((ushort)v[j]);
      float mm = fmaxf(m[j], f);
      z[j] = z[j] * __expf(m[j] - mm) + __expf(f - mm);
      m[j] = mm;
    }
  }
  __shared__ float sm[4][NP], sz[4][NP];
#pragma unroll
  for (int j = 0; j < 8; ++j) { sm[rq][c8 + j] = m[j]; sz[rq][c8 + j] = z[j]; }
  __syncthreads();
  if (rq == 0) {
#pragma unroll
    for (int j = 0; j < 8; ++j) {
      float mj = m[j], zj = z[j];
      for (int q = 1; q < 4; ++q) {
        float m2 = sm[q][c8 + j], z2 = sz[q][c8 + j];
        float mm = fmaxf(mj, m2);
        zj = zj * __expf(mj - mm) + z2 * __expf(m2 - mm);
        mj = mm;
      }
      pm[(size_t)blockIdx.x * NP + c8 + j] = mj;
      pz[(size_t)blockIdx.x * NP + c8 + j] = zj;
    }
  }
}

// parallel column-stat finalize: 8 blocks x 256 thr.
__global__ __launch_bounds__(256) void k_colfinal(const float* __restrict__ pm,
                                                  const float* __restrict__ pz,
                                                  float* __restrict__ colM,
                                                  float* __restrict__ colIZ) {
  const int col = blockIdx.x * 64 + (threadIdx.x & 63);
  const int q = threadIdx.x >> 6;
  float m = -INFINITY, z = 0.f;
  for (int r = q; r < BT / 256; r += 4) {
    float m2 = pm[(size_t)r * NP + col], z2 = pz[(size_t)r * NP + col];
    float mm = fmaxf(m, m2);
    z = z * __expf(m - mm) + z2 * __expf(m2 - mm);
    m = mm;
  }
  __shared__ float sm[4][64], sz[4][64];
  sm[q][threadIdx.x & 63] = m;
  sz[q][threadIdx.x & 63] = z;
  __syncthreads();
  if (q == 0) {
    for (int p = 1; p < 4; ++p) {
      float m2 = sm[p][threadIdx.x], z2 = sz[p][threadIdx.x];
      float mm = fmaxf(m, m2);
      z = z * __expf(m - mm) + z2 * __expf(m2 - mm);
      m = mm;
    }
    colM[col] = m;
    colIZ[col] = 1.f / z;
  }
}

// ---------------------------------------------------------------------------
// Row softmax stats over bf16 mat: one wave per token.
// ---------------------------------------------------------------------------
__global__ __launch_bounds__(256) void k_rowstats(const ushort* __restrict__ mat,
                                                  float* __restrict__ rowM,
                                                  float* __restrict__ rowIZ) {
  const int w = threadIdx.x >> 6;
  const int lane = threadIdx.x & 63;
  const int t = blockIdx.x * 4 + w;
  s16x8 v = *(const s16x8*)(mat + (size_t)t * NP + lane * 8);
  float f[8];
#pragma unroll
  for (int j = 0; j < 8; ++j) f[j] = bf2f((ushort)v[j]);
  float m = f[0];
#pragma unroll
  for (int j = 1; j < 8; ++j) m = fmaxf(m, f[j]);
#pragma unroll
  for (int o = 32; o; o >>= 1) m = fmaxf(m, __shfl_xor(m, o));
  float s = 0.f;
#pragma unroll
  for (int j = 0; j < 8; ++j) s += __expf(f[j] - m);
#pragma unroll
  for (int o = 32; o; o >>= 1) s += __shfl_xor(s, o);
  if (lane == 0) {
    rowM[t] = m;
    rowIZ[t] = 1.f / s;
  }
}

// ---------------------------------------------------------------------------
// Probabilities in bf16 from bf16 mat: Pc[t][s] and Pt[s][t] (stride LDT).
// ---------------------------------------------------------------------------
__global__ __launch_bounds__(256) void k_probs(const ushort* __restrict__ mat,
                                               const float* __restrict__ colM,
                                               const float* __restrict__ colIZ,
                                               const float* __restrict__ rowM,
                                               const float* __restrict__ rowIZ,
                                               ushort* __restrict__ Pc,
                                               ushort* __restrict__ Pt) {
  __shared__ __align__(16) ushort tT[64][64];
  __shared__ float cm[64], cz[64], rm[64], rz[64];
  const int tid = threadIdx.x;
  const int t0 = blockIdx.x * 64, s0 = blockIdx.y * 64;
  if (tid < 64) {
    cm[tid] = colM[s0 + tid]; cz[tid] = colIZ[s0 + tid];
    rm[tid] = rowM[t0 + tid]; rz[tid] = rowIZ[t0 + tid];
  }
  __syncthreads();
#pragma unroll
  for (int i = 0; i < 2; ++i) {
    const int idx = i * 256 + tid;
    const int r = idx >> 3, c8 = (idx & 7) * 8;
    s16x8 v = *(const s16x8*)(mat + (size_t)(t0 + r) * NP + s0 + c8);
    const float mr = rm[r], zr = rz[r];
    s16x8 oc;
#pragma unroll
    for (int j = 0; j < 8; ++j) {
      float f = bf2f((ushort)v[j]);
      oc[j] = (short)f2bf(__expf(f - mr) * zr);
      tT[c8 + j][r ^ (((c8 + j) & 7) << 3)] = f2bf(__expf(f - cm[c8 + j]) * cz[c8 + j]);
    }
    *(s16x8*)(Pc + (size_t)(t0 + r) * NP + s0 + c8) = oc;
  }
  __syncthreads();
#pragma unroll
  for (int i = 0; i < 2; ++i) {
    const int idx = i * 256 + tid;
    const int c = idx >> 3, r8 = (idx & 7) * 8;
    s16x8 o = *(const s16x8*)&tT[c][r8 ^ ((c & 7) << 3)];
    *(s16x8*)(Pt + (size_t)(s0 + c) * LDT + t0 + r8) = o;
  }
}

// ---------------------------------------------------------------------------
// Expert MLP layer (fp32, weight-streaming) — reverted to round-11 form
// (grid (NE, N/64); the round-12 float2 variant halved block count and
// starved memory-bound streaming: +13us regression).
// ---------------------------------------------------------------------------
template <int K, int N, bool RELU>
__global__ __launch_bounds__(256) void k_mlp(const float* __restrict__ X,
                                             const float* __restrict__ W,
                                             const float* __restrict__ bias,
                                             float* __restrict__ Y) {
  __shared__ float xs[NS * K];
  const int tid = threadIdx.x;
  const int e = blockIdx.x;
  const float4* src = (const float4*)(X + (size_t)e * NS * K);
  float4* dst = (float4*)xs;
  constexpr int NV = (NS * K) / (4 * 256);
#pragma unroll
  for (int i = 0; i < NV; ++i) dst[tid + i * 256] = src[tid + i * 256];
  __syncthreads();
  const int j = blockIdx.y * 64 + (tid & 63);
  const int pr = tid >> 6;
  const float* w = W + (size_t)e * K * N + j;
  const float* x0 = xs + pr * K;
  const float* x1 = xs + (pr + 4) * K;
  float a0 = 0.f, a1 = 0.f;
#pragma unroll 8
  for (int k = 0; k < K; ++k) {
    float wv = w[(size_t)k * N];
    a0 += x0[k] * wv;
    a1 += x1[k] * wv;
  }
  const float bb = bias[(size_t)e * N + j];
  a0 += bb;
  a1 += bb;
  if (RELU) {
    a0 = fmaxf(a0, 0.f);
    a1 = fmaxf(a1, 0.f);
  }
  Y[((size_t)e * NS + pr) * N + j] = a0;
  Y[((size_t)e * NS + pr + 4) * N + j] = a1;
}

}  // namespace

extern "C" void kernel_launch(void* const* d_in, const int* in_sizes, int n_in,
                              void* d_out, int out_size, void* d_ws, size_t ws_size,
                              hipStream_t stream) {
  const float* tokens = (const float*)d_in[0];  // [BT, DIM]
  const float* em     = (const float*)d_in[1];  // [DIM, NP]
  const float* W1     = (const float*)d_in[2];
  const float* b1     = (const float*)d_in[3];
  const float* W2     = (const float*)d_in[4];
  const float* b2     = (const float*)d_in[5];
  const float* W3     = (const float*)d_in[6];
  const float* b3     = (const float*)d_in[7];
  float* out = (float*)d_out;

  char* w = (char*)d_ws;
  ushort* matb      = (ushort*)w; w += (size_t)BT * NP * 2;     // 32MB bf16 logits
  ushort* tokens_bf = (ushort*)w; w += (size_t)BT * DIM * 2;    // 64MB
  ushort* tokT      = (ushort*)w; w += (size_t)DIM * LDT * 2;   // 67MB (padded)
  ushort* Pt        = (ushort*)w; w += (size_t)NP * LDT * 2;    // 33.6MB (padded)
  ushort* Pc        = (ushort*)w; w += (size_t)BT * NP * 2;     // 33.5MB
  ushort* emT       = (ushort*)w; w += (size_t)NP * DIM * 2;
  ushort* yhatT     = (ushort*)w; w += (size_t)DIM * NP * 2;
  float*  pm        = (float*)w;  w += (size_t)(BT / 256) * NP * 4;
  float*  pz        = (float*)w;  w += (size_t)(BT / 256) * NP * 4;
  float*  colM      = (float*)w;  w += NP * 4;
  float*  colIZ     = (float*)w;  w += NP * 4;
  float*  rowM      = (float*)w;  w += BT * 4;
  float*  rowIZ     = (float*)w;  w += BT * 4;
  float*  xhat      = (float*)w;  w += (size_t)NP * DIM * 4;
  float*  h1        = (float*)w;  w += (size_t)NP * HID * 4;
  float*  h2        = (float*)w;  w += (size_t)NP * HID * 4;
  float*  yhat      = (float*)w;  w += (size_t)NP * DIM * 4;
  (void)ws_size; (void)in_sizes; (void)n_in; (void)out_size;

  // prep: one pass over fp32 tokens -> rowmajor bf16 + transposed bf16 (padded)
  k_cvt<true, true><<<dim3(BT / 64, DIM / 64), 256, 0, stream>>>(tokens, tokens_bf, tokT, DIM, LDT);
  k_cvt<false, true><<<dim3(DIM / 64, NP / 64), 256, 0, stream>>>(em, nullptr, emT, NP, DIM);
  // 1. routing logits (bf16 out): 256x128 tile, 3-buf deep pipeline
  k_gemm<false, true><<<dim3(NP / 128, BT / 256, 1), 512, 0, stream>>>(tokens_bf, emT, matb, NP, DIM, DIM, DIM);
  // 2. softmax stats
  k_colpart<<<BT / 256, 256, 0, stream>>>(matb, pm, pz);
  k_colfinal<<<NP / 64, 256, 0, stream>>>(pm, pz, colM, colIZ);
  k_rowstats<<<BT / 4, 256, 0, stream>>>(matb, rowM, rowIZ);
  // 3. probabilities in bf16 (Pc rowmajor, Pt transposed+padded)
  k_probs<<<dim3(BT / 64, NP / 64), 256, 0, stream>>>(matb, colM, colIZ, rowM, rowIZ, Pc, Pt);
  // 4. dispatch: xhat = Pt @ tokens  (split-K 16, fp32 atomics), padded strides
  hipMemsetAsync(xhat, 0, (size_t)NP * DIM * 4, stream);
  k_gemm<true, false><<<dim3(DIM / 128, NP / 256, 16), 512, 0, stream>>>(Pt, tokT, xhat, DIM, BT / 16, LDT, LDT);
  // 5. expert MLPs (fp32)
  k_mlp<DIM, HID, true><<<dim3(NE, HID / 64), 256, 0, stream>>>(xhat, W1, b1, h1);
  k_mlp<HID, HID, true><<<dim3(NE, HID / 64), 256, 0, stream>>>(h1, W2, b2, h2);
  k_mlp<HID, DIM, false><<<dim3(NE, DIM / 64), 256, 0, stream>>>(h2, W3, b3, yhat);
  k_cvt<false, true><<<dim3(NP / 64, DIM / 64), 256, 0, stream>>>(yhat, nullptr, yhatT, DIM, NP);
  // 6. combine: out = Pc @ yhat
  k_gemm<false, false><<<dim3(DIM / 128, BT / 256, 1), 512, 0, stream>>>(Pc, yhatT, out, DIM, NP, NP, NP);
}

// Round 14
// 394.579 us; speedup vs baseline: 1.0836x; 1.0836x over previous
//
#include <hip/hip_runtime.h>
#include <math.h>

namespace {

constexpr int BT  = 8 * 4096;   // 32768 tokens
constexpr int DIM = 1024;       // model dim
constexpr int NE  = 64;         // experts
constexpr int NS  = 8;          // slots per expert
constexpr int NP  = NE * NS;    // 512 total slots
constexpr int HID = 256;

typedef float f32x4 __attribute__((ext_vector_type(4)));
typedef __bf16 bf16x8 __attribute__((ext_vector_type(8)));
typedef short s16x8 __attribute__((ext_vector_type(8)));

__device__ __forceinline__ ushort f2bf(float x) {
  union { float f; unsigned u; } a; a.f = x;
  unsigned r = a.u + 0x7FFFu + ((a.u >> 16) & 1u);  // RNE
  return (ushort)(r >> 16);
}
__device__ __forceinline__ float bf2f(ushort u) {
  union { unsigned u; float f; } a; a.u = (unsigned)u << 16;
  return a.f;
}

__device__ __forceinline__ void gload16(const void* g, void* l) {
  __builtin_amdgcn_global_load_lds(
      (const __attribute__((address_space(1))) void*)g,
      (__attribute__((address_space(3))) void*)l, 16, 0, 0);
}

// ---------------------------------------------------------------------------
// bf16 MFMA GEMM — pipeline structure unchanged from round 11 (measured win).
// Tile 256(M)x128(N), BK=64, 8 waves, 3-buffer rotation, one s_barrier +
// counted vmcnt(6) per K-tile, LDS XOR swizzle both-sides, T1 XCD swizzle.
// NEW (CSTAT): fused column-softmax partial stats in the epilogue — the
// routing GEMM's block tile [256 t][128 s] is reduced per-column (online
// max/sumexp) in-register + shfl + LDS merge, writing pm/pz[by][col] in the
// exact layout k_colpart produced. Eliminates colpart's 32MB matb re-read.
// ---------------------------------------------------------------------------
template <bool ATOMIC, bool OBF, bool CSTAT>
__global__ __launch_bounds__(512) void k_gemm(const ushort* __restrict__ A,
                                              const ushort* __restrict__ Bt,
                                              void* __restrict__ Cv,
                                              int N, int kchunk,
                                              int lda, int ldb,
                                              float* __restrict__ pmOut,
                                              float* __restrict__ pzOut) {
  __shared__ __align__(16) ushort As0[256 * 64];
  __shared__ __align__(16) ushort As1[256 * 64];
  __shared__ __align__(16) ushort As2[256 * 64];
  __shared__ __align__(16) ushort Bs0[128 * 64];
  __shared__ __align__(16) ushort Bs1[128 * 64];
  __shared__ __align__(16) ushort Bs2[128 * 64];

  const int tid = threadIdx.x;
  const int wid = tid >> 6;
  const int lane = tid & 63;

  // T1 XCD-chunked swizzle (bijective: nwg % 8 == 0)
  const int gx = gridDim.x, gy = gridDim.y;
  int wg = (blockIdx.z * gy + blockIdx.y) * gx + blockIdx.x;
  const int nwg = gx * gy * gridDim.z;
  wg = (wg & 7) * (nwg >> 3) + (wg >> 3);
  const int bx = wg % gx;
  const int rest = wg / gx;
  const int by = rest % gy;
  const int bz = rest / gy;

  const int n0 = bx * 128;
  const int m0 = by * 256;
  const int kb = bz * kchunk;

  const int w8 = wid * 8;
  const int lr = lane >> 3;
  const int ks = (((lane & 7) ^ lr) * 8);
  const ushort* Asrc = A + (size_t)(m0 + w8 + lr) * lda + ks;
  const ushort* Bsrc = Bt + (size_t)(n0 + w8 + lr) * ldb + ks;

  const int wm64 = (wid >> 1) * 64;
  const int wn64 = (wid & 1) * 64;
  const int fr = lane & 15;
  const int fq = lane >> 4;
  const int fq8 = fq * 8;
  const int frsw = (fr & 7) << 3;

  f32x4 acc[4][4];
#pragma unroll
  for (int i = 0; i < 4; ++i)
#pragma unroll
    for (int j = 0; j < 4; ++j) acc[i][j] = (f32x4){0.f, 0.f, 0.f, 0.f};

  const int nt = kchunk / 64;

#define STAGE6(An_, Bn_, kt_)                                                    \
  do {                                                                           \
    _Pragma("unroll") for (int q = 0; q < 4; ++q)                                \
      gload16(Asrc + (size_t)(q * 64) * lda + (kt_), (An_) + (q * 64 + w8) * 64);\
    _Pragma("unroll") for (int q = 0; q < 2; ++q)                                \
      gload16(Bsrc + (size_t)(q * 64) * ldb + (kt_), (Bn_) + (q * 64 + w8) * 64);\
  } while (0)

#define LD(B_, r_, h_)                                                          \
  __builtin_bit_cast(bf16x8, *(const s16x8*)((B_) + (size_t)(r_) * 64 +         \
                                             (((h_) * 32 + fq8) ^ frsw)))

#define GBLOCK(Ab_, Bb_, An_, Bn_, tt_)                                         \
  do {                                                                          \
    if ((tt_) + 1 < nt) asm volatile("s_waitcnt vmcnt(6)" ::: "memory");        \
    else                asm volatile("s_waitcnt vmcnt(0)" ::: "memory");        \
    __builtin_amdgcn_sched_barrier(0);                                          \
    __builtin_amdgcn_s_barrier();                                               \
    __builtin_amdgcn_sched_barrier(0);                                          \
    if ((tt_) + 2 < nt) STAGE6(An_, Bn_, kb + ((tt_) + 2) * 64);                \
    bf16x8 bfr_[4][2];                                                          \
    _Pragma("unroll") for (int n = 0; n < 4; ++n) {                             \
      bfr_[n][0] = LD(Bb_, wn64 + n * 16 + fr, 0);                              \
      bfr_[n][1] = LD(Bb_, wn64 + n * 16 + fr, 1);                              \
    }                                                                           \
    _Pragma("unroll") for (int m = 0; m < 4; ++m) {                             \
      bf16x8 a0_ = LD(Ab_, wm64 + m * 16 + fr, 0);                              \
      bf16x8 a1_ = LD(Ab_, wm64 + m * 16 + fr, 1);                              \
      __builtin_amdgcn_s_setprio(1);                                            \
      _Pragma("unroll") for (int n = 0; n < 4; ++n)                             \
        acc[m][n] = __builtin_amdgcn_mfma_f32_16x16x32_bf16(a0_, bfr_[n][0],    \
                                                            acc[m][n], 0, 0, 0);\
      _Pragma("unroll") for (int n = 0; n < 4; ++n)                             \
        acc[m][n] = __builtin_amdgcn_mfma_f32_16x16x32_bf16(a1_, bfr_[n][1],    \
                                                            acc[m][n], 0, 0, 0);\
      __builtin_amdgcn_s_setprio(0);                                            \
    }                                                                           \
  } while (0)

  STAGE6(As0, Bs0, kb);
  STAGE6(As1, Bs1, kb + 64);
  int t = 0;
  for (; t + 3 <= nt; t += 3) {
    GBLOCK(As0, Bs0, As2, Bs2, t);
    GBLOCK(As1, Bs1, As0, Bs0, t + 1);
    GBLOCK(As2, Bs2, As1, Bs1, t + 2);
  }
  if (t < nt) { GBLOCK(As0, Bs0, As2, Bs2, t); ++t; }
  if (t < nt) { GBLOCK(As1, Bs1, As0, Bs0, t); ++t; }
#undef GBLOCK
#undef LD
#undef STAGE6

  // C/D layout: col = lane&15, row = (lane>>4)*4 + reg   [m89-verified]
  if (OBF) {
    ushort* Cb = (ushort*)Cv + (size_t)(m0 + wm64 + fq * 4) * N + n0 + wn64 + fr;
#pragma unroll
    for (int m = 0; m < 4; ++m)
#pragma unroll
      for (int n = 0; n < 4; ++n)
#pragma unroll
        for (int r = 0; r < 4; ++r)
          Cb[(size_t)(m * 16 + r) * N + n * 16] = f2bf(acc[m][n][r]);
  } else {
    float* Cb = (float*)Cv + (size_t)(m0 + wm64 + fq * 4) * N + n0 + wn64 + fr;
#pragma unroll
    for (int m = 0; m < 4; ++m)
#pragma unroll
      for (int n = 0; n < 4; ++n)
#pragma unroll
        for (int r = 0; r < 4; ++r) {
          float* p = Cb + (size_t)(m * 16 + r) * N + n * 16;
          if (ATOMIC) atomicAdd(p, acc[m][n][r]);
          else *p = acc[m][n][r];
        }
  }

  if (CSTAT) {
    // per-lane online max/sumexp over the 16 row-values of each of 4 columns
    float cm_[4], cz_[4];
#pragma unroll
    for (int n = 0; n < 4; ++n) { cm_[n] = -INFINITY; cz_[n] = 0.f; }
#pragma unroll
    for (int m = 0; m < 4; ++m)
#pragma unroll
      for (int n = 0; n < 4; ++n)
#pragma unroll
        for (int r = 0; r < 4; ++r) {
          float v = acc[m][n][r];
          float mm = fmaxf(cm_[n], v);
          cz_[n] = cz_[n] * __expf(cm_[n] - mm) + __expf(v - mm);
          cm_[n] = mm;
        }
    // reduce across the 4 fq row-groups (lanes 16/32 apart)
#pragma unroll
    for (int off = 16; off <= 32; off <<= 1)
#pragma unroll
      for (int n = 0; n < 4; ++n) {
        float m2 = __shfl_xor(cm_[n], off);
        float z2 = __shfl_xor(cz_[n], off);
        float mm = fmaxf(cm_[n], m2);
        cz_[n] = cz_[n] * __expf(cm_[n] - mm) + z2 * __expf(m2 - mm);
        cm_[n] = mm;
      }
    __syncthreads();  // all waves done with LDS buffers -> reuse As0 as scratch
    float* smx = (float*)As0;      // [4 m-waves][128 cols]
    float* smz = smx + 4 * 128;
    const int mrow = wid >> 1;
    if (lane < 16) {
#pragma unroll
      for (int n = 0; n < 4; ++n) {
        smx[mrow * 128 + wn64 + n * 16 + lane] = cm_[n];
        smz[mrow * 128 + wn64 + n * 16 + lane] = cz_[n];
      }
    }
    __syncthreads();
    if (tid < 128) {
      float m = smx[tid], z = smz[tid];
#pragma unroll
      for (int p = 1; p < 4; ++p) {
        float m2 = smx[p * 128 + tid], z2 = smz[p * 128 + tid];
        float mm = fmaxf(m, m2);
        z = z * __expf(m - mm) + z2 * __expf(m2 - mm);
        m = mm;
      }
      pmOut[(size_t)by * NP + n0 + tid] = m;
      pzOut[(size_t)by * NP + n0 + tid] = z;
    }
  }
}

// ---------------------------------------------------------------------------
// fp32 [R][C] -> bf16 rowmajor and/or bf16 transposed (row stride ldt).
// ---------------------------------------------------------------------------
template <bool ROWM, bool TRANSP>
__global__ __launch_bounds__(256) void k_cvt(const float* __restrict__ X,
                                             ushort* __restrict__ Yrm,
                                             ushort* __restrict__ Yt,
                                             int Cc, int ldt) {
  __shared__ __align__(16) ushort tT[64][64];
  const int tid = threadIdx.x;
  const int r0 = blockIdx.x * 64, c0 = blockIdx.y * 64;
#pragma unroll
  for (int i = 0; i < 4; ++i) {
    const int idx = i * 256 + tid;
    const int r = idx >> 4, c4 = (idx & 15) * 4;
    float4 v = *(const float4*)(X + (size_t)(r0 + r) * Cc + c0 + c4);
    ushort u[4] = {f2bf(v.x), f2bf(v.y), f2bf(v.z), f2bf(v.w)};
    if (ROWM) {
      ushort4 o = make_ushort4(u[0], u[1], u[2], u[3]);
      *(ushort4*)(Yrm + (size_t)(r0 + r) * Cc + c0 + c4) = o;
    }
    if (TRANSP) {
#pragma unroll
      for (int j = 0; j < 4; ++j)
        tT[c4 + j][r ^ (((c4 + j) & 7) << 3)] = u[j];
    }
  }
  if (TRANSP) {
    __syncthreads();
#pragma unroll
    for (int i = 0; i < 2; ++i) {
      const int idx = i * 256 + tid;
      const int c = idx >> 3, r8 = (idx & 7) * 8;
      s16x8 o = *(const s16x8*)&tT[c][r8 ^ ((c & 7) << 3)];
      *(s16x8*)(Yt + (size_t)(c0 + c) * ldt + r0 + r8) = o;
    }
  }
}

// parallel column-stat finalize: 8 blocks x 256 thr.
__global__ __launch_bounds__(256) void k_colfinal(const float* __restrict__ pm,
                                                  const float* __restrict__ pz,
                                                  float* __restrict__ colM,
                                                  float* __restrict__ colIZ) {
  const int col = blockIdx.x * 64 + (threadIdx.x & 63);
  const int q = threadIdx.x >> 6;
  float m = -INFINITY, z = 0.f;
  for (int r = q; r < BT / 256; r += 4) {
    float m2 = pm[(size_t)r * NP + col], z2 = pz[(size_t)r * NP + col];
    float mm = fmaxf(m, m2);
    z = z * __expf(m - mm) + z2 * __expf(m2 - mm);
    m = mm;
  }
  __shared__ float sm[4][64], sz[4][64];
  sm[q][threadIdx.x & 63] = m;
  sz[q][threadIdx.x & 63] = z;
  __syncthreads();
  if (q == 0) {
    for (int p = 1; p < 4; ++p) {
      float m2 = sm[p][threadIdx.x], z2 = sz[p][threadIdx.x];
      float mm = fmaxf(m, m2);
      z = z * __expf(m - mm) + z2 * __expf(m2 - mm);
      m = mm;
    }
    colM[col] = m;
    colIZ[col] = 1.f / z;
  }
}

// ---------------------------------------------------------------------------
// Row softmax stats over bf16 mat: one wave per token.
// ---------------------------------------------------------------------------
__global__ __launch_bounds__(256) void k_rowstats(const ushort* __restrict__ mat,
                                                  float* __restrict__ rowM,
                                                  float* __restrict__ rowIZ) {
  const int w = threadIdx.x >> 6;
  const int lane = threadIdx.x & 63;
  const int t = blockIdx.x * 4 + w;
  s16x8 v = *(const s16x8*)(mat + (size_t)t * NP + lane * 8);
  float f[8];
#pragma unroll
  for (int j = 0; j < 8; ++j) f[j] = bf2f((ushort)v[j]);
  float m = f[0];
#pragma unroll
  for (int j = 1; j < 8; ++j) m = fmaxf(m, f[j]);
#pragma unroll
  for (int o = 32; o; o >>= 1) m = fmaxf(m, __shfl_xor(m, o));
  float s = 0.f;
#pragma unroll
  for (int j = 0; j < 8; ++j) s += __expf(f[j] - m);
#pragma unroll
  for (int o = 32; o; o >>= 1) s += __shfl_xor(s, o);
  if (lane == 0) {
    rowM[t] = m;
    rowIZ[t] = 1.f / s;
  }
}

// ---------------------------------------------------------------------------
// Probabilities in bf16 from bf16 mat: Pc[t][s] and Pt[s][t] (stride BT).
// ---------------------------------------------------------------------------
__global__ __launch_bounds__(256) void k_probs(const ushort* __restrict__ mat,
                                               const float* __restrict__ colM,
                                               const float* __restrict__ colIZ,
                                               const float* __restrict__ rowM,
                                               const float* __restrict__ rowIZ,
                                               ushort* __restrict__ Pc,
                                               ushort* __restrict__ Pt) {
  __shared__ __align__(16) ushort tT[64][64];
  __shared__ float cm[64], cz[64], rm[64], rz[64];
  const int tid = threadIdx.x;
  const int t0 = blockIdx.x * 64, s0 = blockIdx.y * 64;
  if (tid < 64) {
    cm[tid] = colM[s0 + tid]; cz[tid] = colIZ[s0 + tid];
    rm[tid] = rowM[t0 + tid]; rz[tid] = rowIZ[t0 + tid];
  }
  __syncthreads();
#pragma unroll
  for (int i = 0; i < 2; ++i) {
    const int idx = i * 256 + tid;
    const int r = idx >> 3, c8 = (idx & 7) * 8;
    s16x8 v = *(const s16x8*)(mat + (size_t)(t0 + r) * NP + s0 + c8);
    const float mr = rm[r], zr = rz[r];
    s16x8 oc;
#pragma unroll
    for (int j = 0; j < 8; ++j) {
      float f = bf2f((ushort)v[j]);
      oc[j] = (short)f2bf(__expf(f - mr) * zr);
      tT[c8 + j][r ^ (((c8 + j) & 7) << 3)] = f2bf(__expf(f - cm[c8 + j]) * cz[c8 + j]);
    }
    *(s16x8*)(Pc + (size_t)(t0 + r) * NP + s0 + c8) = oc;
  }
  __syncthreads();
#pragma unroll
  for (int i = 0; i < 2; ++i) {
    const int idx = i * 256 + tid;
    const int c = idx >> 3, r8 = (idx & 7) * 8;
    s16x8 o = *(const s16x8*)&tT[c][r8 ^ ((c & 7) << 3)];
    *(s16x8*)(Pt + (size_t)(s0 + c) * BT + t0 + r8) = o;
  }
}

// ---------------------------------------------------------------------------
// Expert MLP layer (fp32, weight-streaming) — round-11 measured-good form.
// ---------------------------------------------------------------------------
template <int K, int N, bool RELU>
__global__ __launch_bounds__(256) void k_mlp(const float* __restrict__ X,
                                             const float* __restrict__ W,
                                             const float* __restrict__ bias,
                                             float* __restrict__ Y) {
  __shared__ float xs[NS * K];
  const int tid = threadIdx.x;
  const int e = blockIdx.x;
  const float4* src = (const float4*)(X + (size_t)e * NS * K);
  float4* dst = (float4*)xs;
  constexpr int NV = (NS * K) / (4 * 256);
#pragma unroll
  for (int i = 0; i < NV; ++i) dst[tid + i * 256] = src[tid + i * 256];
  __syncthreads();
  const int j = blockIdx.y * 64 + (tid & 63);
  const int pr = tid >> 6;
  const float* w = W + (size_t)e * K * N + j;
  const float* x0 = xs + pr * K;
  const float* x1 = xs + (pr + 4) * K;
  float a0 = 0.f, a1 = 0.f;
#pragma unroll 8
  for (int k = 0; k < K; ++k) {
    float wv = w[(size_t)k * N];
    a0 += x0[k] * wv;
    a1 += x1[k] * wv;
  }
  const float bb = bias[(size_t)e * N + j];
  a0 += bb;
  a1 += bb;
  if (RELU) {
    a0 = fmaxf(a0, 0.f);
    a1 = fmaxf(a1, 0.f);
  }
  Y[((size_t)e * NS + pr) * N + j] = a0;
  Y[((size_t)e * NS + pr + 4) * N + j] = a1;
}

}  // namespace

extern "C" void kernel_launch(void* const* d_in, const int* in_sizes, int n_in,
                              void* d_out, int out_size, void* d_ws, size_t ws_size,
                              hipStream_t stream) {
  const float* tokens = (const float*)d_in[0];  // [BT, DIM]
  const float* em     = (const float*)d_in[1];  // [DIM, NP]
  const float* W1     = (const float*)d_in[2];
  const float* b1     = (const float*)d_in[3];
  const float* W2     = (const float*)d_in[4];
  const float* b2     = (const float*)d_in[5];
  const float* W3     = (const float*)d_in[6];
  const float* b3     = (const float*)d_in[7];
  float* out = (float*)d_out;

  char* w = (char*)d_ws;
  ushort* matb      = (ushort*)w; w += (size_t)BT * NP * 2;    // 32MB bf16 logits
  ushort* tokens_bf = (ushort*)w; w += (size_t)BT * DIM * 2;   // 64MB
  ushort* tokT      = (ushort*)w; w += (size_t)DIM * BT * 2;   // 64MB
  ushort* Pt        = (ushort*)w; w += (size_t)NP * BT * 2;    // 33.5MB
  ushort* Pc        = (ushort*)w; w += (size_t)BT * NP * 2;    // 33.5MB
  ushort* emT       = (ushort*)w; w += (size_t)NP * DIM * 2;
  ushort* yhatT     = (ushort*)w; w += (size_t)DIM * NP * 2;
  float*  pm        = (float*)w;  w += (size_t)(BT / 256) * NP * 4;
  float*  pz        = (float*)w;  w += (size_t)(BT / 256) * NP * 4;
  float*  colM      = (float*)w;  w += NP * 4;
  float*  colIZ     = (float*)w;  w += NP * 4;
  float*  rowM      = (float*)w;  w += BT * 4;
  float*  rowIZ     = (float*)w;  w += BT * 4;
  float*  xhat      = (float*)w;  w += (size_t)NP * DIM * 4;
  float*  h1        = (float*)w;  w += (size_t)NP * HID * 4;
  float*  h2        = (float*)w;  w += (size_t)NP * HID * 4;
  float*  yhat      = (float*)w;  w += (size_t)NP * DIM * 4;
  (void)ws_size; (void)in_sizes; (void)n_in; (void)out_size;

  // prep: one pass over fp32 tokens -> rowmajor bf16 + transposed bf16
  k_cvt<true, true><<<dim3(BT / 64, DIM / 64), 256, 0, stream>>>(tokens, tokens_bf, tokT, DIM, BT);
  k_cvt<false, true><<<dim3(DIM / 64, NP / 64), 256, 0, stream>>>(em, nullptr, emT, NP, DIM);
  // 1. routing logits (bf16 out) + fused column-stat partials (CSTAT)
  k_gemm<false, true, true><<<dim3(NP / 128, BT / 256, 1), 512, 0, stream>>>(
      tokens_bf, emT, matb, NP, DIM, DIM, DIM, pm, pz);
  // 2. softmax stats (colpart now fused into GEMM1 epilogue)
  k_colfinal<<<NP / 64, 256, 0, stream>>>(pm, pz, colM, colIZ);
  k_rowstats<<<BT / 4, 256, 0, stream>>>(matb, rowM, rowIZ);
  // 3. probabilities in bf16 (Pc rowmajor, Pt transposed)
  k_probs<<<dim3(BT / 64, NP / 64), 256, 0, stream>>>(matb, colM, colIZ, rowM, rowIZ, Pc, Pt);
  // 4. dispatch: xhat = Pt @ tokens  (split-K 16, fp32 atomics)
  hipMemsetAsync(xhat, 0, (size_t)NP * DIM * 4, stream);
  k_gemm<true, false, false><<<dim3(DIM / 128, NP / 256, 16), 512, 0, stream>>>(
      Pt, tokT, xhat, DIM, BT / 16, BT, BT, nullptr, nullptr);
  // 5. expert MLPs (fp32)
  k_mlp<DIM, HID, true><<<dim3(NE, HID / 64), 256, 0, stream>>>(xhat, W1, b1, h1);
  k_mlp<HID, HID, true><<<dim3(NE, HID / 64), 256, 0, stream>>>(h1, W2, b2, h2);
  k_mlp<HID, DIM, false><<<dim3(NE, DIM / 64), 256, 0, stream>>>(h2, W3, b3, yhat);
  k_cvt<false, true><<<dim3(NP / 64, DIM / 64), 256, 0, stream>>>(yhat, nullptr, yhatT, DIM, NP);
  // 6. combine: out = Pc @ yhat
  k_gemm<false, false, false><<<dim3(DIM / 128, BT / 256, 1), 512, 0, stream>>>(
      Pc, yhatT, out, DIM, NP, NP, NP, nullptr, nullptr);
}